// Round 3
// baseline (172.447 us; speedup 1.0000x reference)
//
#include <hip/hip_runtime.h>
#include <hip/hip_bf16.h>
#include <cstdint>

#define BB 32
#define LD 2048
#define LQ 512
#define DD 256
#define BM 128
#define BN 128
#define BK 64

typedef _Float16 half8 __attribute__((ext_vector_type(8)));
typedef _Float16 half4 __attribute__((ext_vector_type(4)));
typedef float float4v __attribute__((ext_vector_type(4)));

// tanh(x) = 1 - 2/(exp2(2*log2e*x)+1); v_exp_f32 + v_rcp_f32, no IEEE-div sequence.
// x->+inf: exp2->inf, rcp->0, result 1. x->-inf: exp2->0, rcp->1, result -1.
__device__ __forceinline__ float tanh_fast(float x) {
    float t = __builtin_amdgcn_exp2f(x * 2.885390081777927f); // 2*log2(e)
    float r = __builtin_amdgcn_rcpf(t + 1.0f);
    return fmaf(-2.0f, r, 1.0f);
}

// K1: per-batch tanh(Q Doc^T) with fused row/col sums into logits (never materializes S).
// fp32 inputs, in-register cvt to f16 during LDS staging (no separate conversion pass).
// 128x128 tile, BK=64, 4 waves each computing a 64x64 quadrant (4x4 MFMA 16x16x32, 2 k-steps).
// LDS XOR-swizzle: 8-f16 group g of row r lives at phys chunk g^(r&7); fragment reads hit
// all 8 bank groups 2-way (free). Verified 0 bank conflicts in R2.
__global__ __launch_bounds__(256) void k1(const float* __restrict__ qsrc,
                                          const float* __restrict__ dsrc,
                                          float* __restrict__ alog,   // [B][LD]
                                          float* __restrict__ blog) { // [B][LQ]
    __shared__ _Float16 sQ[BM * BK]; // 16KB
    __shared__ _Float16 sD[BN * BK]; // 16KB
    const int bq = blockIdx.x, bt = blockIdx.y, b = blockIdx.z;
    const int tid = threadIdx.x;
    const int lane = tid & 63;
    const int wave = tid >> 6;
    const int r16 = lane & 15;
    const int q4 = lane >> 4;
    const int mb = (wave >> 1) * 64, nb = (wave & 1) * 64;

    float4v acc[4][4];
    float4v zero = {0.f, 0.f, 0.f, 0.f};
#pragma unroll
    for (int m = 0; m < 4; m++)
#pragma unroll
        for (int n = 0; n < 4; n++) acc[m][n] = zero;

    // staging map: thread -> (row r0+16i, float4 col c) of the 128x64 fp32 tile
    const int r0 = tid >> 4;              // 0..15
    const int c = tid & 15;               // float4 within row (64 floats)
    const int c2 = c >> 1, hlf = c & 1;   // 8-f16 logical group + half
    const int p = c2 ^ (r0 & 7);          // phys chunk (row&7 == r0&7, since stride 16 rows)
    const int ldsoff = r0 * BK + p * 8 + hlf * 4;
    const float* Qf = qsrc + ((size_t)b * LQ + bq * BM) * DD + (size_t)r0 * DD + 4 * c;
    const float* Df = dsrc + ((size_t)b * LD + bt * BN) * DD + (size_t)r0 * DD + 4 * c;

    for (int kk = 0; kk < DD; kk += BK) {
        __syncthreads(); // previous iteration's LDS reads done
#pragma unroll
        for (int i = 0; i < 8; i++) {
            float4v v = *(const float4v*)(Qf + kk + (size_t)i * 16 * DD);
            half4 h = {(_Float16)v[0], (_Float16)v[1], (_Float16)v[2], (_Float16)v[3]};
            *(half4*)(&sQ[ldsoff + i * 16 * BK]) = h;
            float4v w = *(const float4v*)(Df + kk + (size_t)i * 16 * DD);
            half4 h2 = {(_Float16)w[0], (_Float16)w[1], (_Float16)w[2], (_Float16)w[3]};
            *(half4*)(&sD[ldsoff + i * 16 * BK]) = h2;
        }
        __syncthreads(); // staging complete

#pragma unroll
        for (int kk2 = 0; kk2 < 2; kk2++) {
            const int sw = ((4 * kk2 + q4) ^ (r16 & 7)) * 8;
            half8 af[4], bf[4];
#pragma unroll
            for (int m = 0; m < 4; m++) af[m] = *(const half8*)(&sQ[(mb + 16 * m + r16) * BK + sw]);
#pragma unroll
            for (int n = 0; n < 4; n++) bf[n] = *(const half8*)(&sD[(nb + 16 * n + r16) * BK + sw]);
#pragma unroll
            for (int m = 0; m < 4; m++)
#pragma unroll
                for (int n = 0; n < 4; n++)
                    acc[m][n] = __builtin_amdgcn_mfma_f32_16x16x32_f16(af[m], bf[n], acc[m][n], 0, 0, 0);
        }
    }

    // Epilogue: tanh, then row sums (-> beta logits over q) and col sums (-> alpha logits over t).
    // C/D layout: row = 4*q4 + r, col = lane&15.
    float rsum[4][4];
    float csum[4];
#pragma unroll
    for (int m = 0; m < 4; m++)
#pragma unroll
        for (int r = 0; r < 4; r++) rsum[m][r] = 0.f;
#pragma unroll
    for (int n = 0; n < 4; n++) csum[n] = 0.f;

#pragma unroll
    for (int m = 0; m < 4; m++)
#pragma unroll
        for (int n = 0; n < 4; n++) {
            float t0 = tanh_fast(acc[m][n][0]);
            float t1 = tanh_fast(acc[m][n][1]);
            float t2 = tanh_fast(acc[m][n][2]);
            float t3 = tanh_fast(acc[m][n][3]);
            csum[n] += t0 + t1 + t2 + t3;
            rsum[m][0] += t0;
            rsum[m][1] += t1;
            rsum[m][2] += t2;
            rsum[m][3] += t3;
        }

#pragma unroll
    for (int m = 0; m < 4; m++) {
#pragma unroll
        for (int r = 0; r < 4; r++) {
            float v = rsum[m][r];
            v += __shfl_xor(v, 1);
            v += __shfl_xor(v, 2);
            v += __shfl_xor(v, 4);
            v += __shfl_xor(v, 8);
            rsum[m][r] = v;
        }
        if (r16 < 4) {
            float v = (r16 == 0) ? rsum[m][0] : (r16 == 1) ? rsum[m][1] : (r16 == 2) ? rsum[m][2] : rsum[m][3];
            atomicAdd(blog + b * LQ + bq * BM + mb + 16 * m + 4 * q4 + r16, v);
        }
    }
#pragma unroll
    for (int n = 0; n < 4; n++) {
        float v = csum[n];
        v += __shfl_xor(v, 16);
        v += __shfl_xor(v, 32);
        if (lane < 16) atomicAdd(alog + b * LD + bt * BN + nb + 16 * n + lane, v);
    }
}

// K2: alpha = softmax(alog)*dmask renormalized; beta likewise. One block per softmax row.
__global__ __launch_bounds__(256) void k2(const float* __restrict__ alog, const float* __restrict__ blog,
                                          const float* __restrict__ dmask, const float* __restrict__ qmask,
                                          float* __restrict__ alpha, float* __restrict__ beta) {
    int blk = blockIdx.x;
    const float *lg, *mk;
    float* out;
    int n;
    if (blk < BB) {
        lg = alog + blk * LD; mk = dmask + blk * LD; out = alpha + blk * LD; n = LD;
    } else {
        int b = blk - BB;
        lg = blog + b * LQ; mk = qmask + b * LQ; out = beta + b * LQ; n = LQ;
    }
    int tid = threadIdx.x, lane = tid & 63, wave = tid >> 6;
    __shared__ float sm[4], ss[4];
    float mx = -3.0e38f;
    for (int i = tid; i < n; i += 256) mx = fmaxf(mx, lg[i]);
#pragma unroll
    for (int s = 1; s < 64; s <<= 1) mx = fmaxf(mx, __shfl_xor(mx, s));
    if (lane == 0) sm[wave] = mx;
    __syncthreads();
    mx = fmaxf(fmaxf(sm[0], sm[1]), fmaxf(sm[2], sm[3]));
    const float L2E = 1.4426950408889634f;
    float sum = 0.f;
    for (int i = tid; i < n; i += 256) sum += __builtin_amdgcn_exp2f((lg[i] - mx) * L2E) * mk[i];
#pragma unroll
    for (int s = 1; s < 64; s <<= 1) sum += __shfl_xor(sum, s);
    if (lane == 0) ss[wave] = sum;
    __syncthreads();
    sum = ss[0] + ss[1] + ss[2] + ss[3];
    float inv = 1.0f / sum;
    for (int i = tid; i < n; i += 256)
        out[i] = __builtin_amdgcn_exp2f((lg[i] - mx) * L2E) * mk[i] * inv;
}

// K3: weighted pooling, fp32 sources, coalesced float4 loads. Block = (b, 128-position chunk).
// Thread (g=tid>>5, c=tid&31): owns d-slice [8c,8c+8), strides g over positions.
__global__ __launch_bounds__(256) void k3(const float* __restrict__ docf, const float* __restrict__ qryf,
                                          const float* __restrict__ alpha, const float* __restrict__ beta,
                                          float* __restrict__ out) {
    __shared__ float sm[8 * DD];
    int blk = blockIdx.x, tid = threadIdx.x;
    const float* srcf;
    const float* w;
    float* dst;
    if (blk < BB * 16) {
        int b = blk >> 4, ch = blk & 15;
        srcf = docf + ((size_t)b * LD + ch * 128) * DD;
        w = alpha + b * LD + ch * 128;
        dst = out + b * 2 * DD;
    } else {
        int k = blk - BB * 16;
        int b = k >> 2, ch = k & 3;
        srcf = qryf + ((size_t)b * LQ + ch * 128) * DD;
        w = beta + b * LQ + ch * 128;
        dst = out + b * 2 * DD + DD;
    }
    int g = tid >> 5, c = tid & 31;
    float acc[8];
#pragma unroll
    for (int j = 0; j < 8; j++) acc[j] = 0.f;
    for (int r = 0; r < 16; r++) {
        int t = r * 8 + g;
        float wt = w[t];
        const float4v* p = (const float4v*)(srcf + (size_t)t * DD + c * 8);
        float4v x0 = p[0], x1 = p[1];
#pragma unroll
        for (int j = 0; j < 4; j++) { acc[j] += wt * x0[j]; acc[4 + j] += wt * x1[j]; }
    }
#pragma unroll
    for (int j = 0; j < 8; j++) sm[g * DD + c * 8 + j] = acc[j];
    __syncthreads();
    float s = 0.f;
#pragma unroll
    for (int g2 = 0; g2 < 8; g2++) s += sm[g2 * DD + tid];
    atomicAdd(dst + tid, s);
}

extern "C" void kernel_launch(void* const* d_in, const int* in_sizes, int n_in,
                              void* d_out, int out_size, void* d_ws, size_t ws_size,
                              hipStream_t stream) {
    (void)in_sizes; (void)n_in; (void)out_size; (void)ws_size;
    const float* doc = (const float*)d_in[0];
    const float* qry = (const float*)d_in[1];
    const float* dmask = (const float*)d_in[2];
    const float* qmask = (const float*)d_in[3];
    float* out = (float*)d_out;

    float* alog = (float*)d_ws;                 // [B][LD]
    float* blog = alog + BB * LD;               // [B][LQ]
    float* alpha = blog + BB * LQ;              // [B][LD]
    float* beta = alpha + BB * LD;              // [B][LQ]

    hipMemsetAsync(alog, 0, (size_t)(BB * LD + BB * LQ) * 4, stream);
    hipMemsetAsync(d_out, 0, (size_t)BB * 2 * DD * 4, stream);

    k1<<<dim3(LQ / BM, LD / BN, BB), 256, 0, stream>>>(qry, doc, alog, blog);
    k2<<<2 * BB, 256, 0, stream>>>(alog, blog, dmask, qmask, alpha, beta);
    k3<<<BB * 16 + BB * 4, 256, 0, stream>>>(doc, qry, alpha, beta, out);
}

// Round 4
// 165.754 us; speedup vs baseline: 1.0404x; 1.0404x over previous
//
#include <hip/hip_runtime.h>
#include <hip/hip_bf16.h>
#include <cstdint>

#define BB 32
#define LD 2048
#define LQ 512
#define DD 256
#define BM 256
#define BN 256
#define BK 64

typedef _Float16 half8 __attribute__((ext_vector_type(8)));
typedef _Float16 half4 __attribute__((ext_vector_type(4)));
typedef float float4v __attribute__((ext_vector_type(4)));

// tanh(x) = 1 - 2/(exp2(2*log2e*x)+1); v_exp_f32 + v_rcp_f32. Saturates correctly at +-inf.
__device__ __forceinline__ float tanh_fast(float x) {
    float t = __builtin_amdgcn_exp2f(x * 2.885390081777927f); // 2*log2(e)
    float r = __builtin_amdgcn_rcpf(t + 1.0f);
    return fmaf(-2.0f, r, 1.0f);
}

// K1: per-batch tanh(Q Doc^T), fused row/col sums -> PARTIAL logits (no atomics, no memset).
// 256x256 tile, 512 threads (8 waves as 2x4), BK=64, fp32->f16 cvt during LDS staging.
// Wave w: rows [wr*128,+128) x cols [wc*64,+64) => 8x4 MFMA 16x16x32 tiles, 2 ksteps/iter.
// LDS XOR-swizzle (verified 0 conflicts in R2): 8-f16 group g of row r at phys chunk g^(r&7).
// Outputs: pb[bt][b][q] = partial row sums (this block's 256 doc cols);
//          pa[bq][b][t] = partial col sums (this block's 256 query rows).
__global__ __launch_bounds__(512, 2) void k1(const float* __restrict__ qsrc,
                                             const float* __restrict__ dsrc,
                                             float* __restrict__ pa,   // [2][B][LD]
                                             float* __restrict__ pb) { // [8][B][LQ]
    __shared__ _Float16 sQ[BM * BK]; // 32KB
    __shared__ _Float16 sD[BN * BK]; // 32KB
    __shared__ float srow[BM][4];    // 4KB: per-row partial sums by wc
    __shared__ float scol[BN][2];    // 2KB: per-col partial sums by wr
    const int bq = blockIdx.x, bt = blockIdx.y, b = blockIdx.z;
    const int tid = threadIdx.x;
    const int lane = tid & 63;
    const int wave = tid >> 6;
    const int r16 = lane & 15;
    const int q4 = lane >> 4;
    const int wr = wave >> 2, wc = wave & 3;
    const int mb = wr * 128, nb = wc * 64;

    float4v acc[8][4];
    float4v zero = {0.f, 0.f, 0.f, 0.f};
#pragma unroll
    for (int m = 0; m < 8; m++)
#pragma unroll
        for (int n = 0; n < 4; n++) acc[m][n] = zero;

    // staging map: thread -> (row r0+32i, float4 col c) of the 256x64 fp32 tile
    const int r0 = tid >> 4;              // 0..31
    const int c = tid & 15;               // float4 within row (64 floats)
    const int c2 = c >> 1, hlf = c & 1;   // 8-f16 logical group + half
    const int p = c2 ^ (r0 & 7);          // row&7 == r0&7 (stride 32 rows)
    const int ldsoff = r0 * BK + p * 8 + hlf * 4;
    const float* Qf = qsrc + ((size_t)b * LQ + bq * BM + r0) * DD + 4 * c;
    const float* Df = dsrc + ((size_t)b * LD + bt * BN + r0) * DD + 4 * c;

    for (int kk = 0; kk < DD; kk += BK) {
        __syncthreads(); // previous iteration's LDS reads done
#pragma unroll
        for (int i = 0; i < 8; i++) {
            float4v v = *(const float4v*)(Qf + kk + (size_t)i * 32 * DD);
            half4 h = {(_Float16)v[0], (_Float16)v[1], (_Float16)v[2], (_Float16)v[3]};
            *(half4*)(&sQ[ldsoff + i * 32 * BK]) = h;
            float4v w = *(const float4v*)(Df + kk + (size_t)i * 32 * DD);
            half4 h2 = {(_Float16)w[0], (_Float16)w[1], (_Float16)w[2], (_Float16)w[3]};
            *(half4*)(&sD[ldsoff + i * 32 * BK]) = h2;
        }
        __syncthreads(); // staging complete

#pragma unroll
        for (int kk2 = 0; kk2 < 2; kk2++) {
            const int sw = ((4 * kk2 + q4) ^ (r16 & 7)) * 8;
            half8 af[8], bf[4];
#pragma unroll
            for (int m = 0; m < 8; m++) af[m] = *(const half8*)(&sQ[(mb + 16 * m + r16) * BK + sw]);
#pragma unroll
            for (int n = 0; n < 4; n++) bf[n] = *(const half8*)(&sD[(nb + 16 * n + r16) * BK + sw]);
#pragma unroll
            for (int m = 0; m < 8; m++)
#pragma unroll
                for (int n = 0; n < 4; n++)
                    acc[m][n] = __builtin_amdgcn_mfma_f32_16x16x32_f16(af[m], bf[n], acc[m][n], 0, 0, 0);
        }
    }

    // Epilogue. C/D layout: row = 4*q4 + r, col = r16.
    float rsum[8][4];
    float csum[4];
#pragma unroll
    for (int m = 0; m < 8; m++)
#pragma unroll
        for (int r = 0; r < 4; r++) rsum[m][r] = 0.f;
#pragma unroll
    for (int n = 0; n < 4; n++) csum[n] = 0.f;

#pragma unroll
    for (int m = 0; m < 8; m++)
#pragma unroll
        for (int n = 0; n < 4; n++) {
            float t0 = tanh_fast(acc[m][n][0]);
            float t1 = tanh_fast(acc[m][n][1]);
            float t2 = tanh_fast(acc[m][n][2]);
            float t3 = tanh_fast(acc[m][n][3]);
            csum[n] += t0 + t1 + t2 + t3;
            rsum[m][0] += t0;
            rsum[m][1] += t1;
            rsum[m][2] += t2;
            rsum[m][3] += t3;
        }

    // row sums within wave slice (64 cols): butterfly over r16; lanes r16<4 hold rows 4*q4+r16
#pragma unroll
    for (int m = 0; m < 8; m++) {
#pragma unroll
        for (int r = 0; r < 4; r++) {
            float v = rsum[m][r];
            v += __shfl_xor(v, 1);
            v += __shfl_xor(v, 2);
            v += __shfl_xor(v, 4);
            v += __shfl_xor(v, 8);
            rsum[m][r] = v;
        }
        if (r16 < 4) {
            float v = (r16 == 0) ? rsum[m][0] : (r16 == 1) ? rsum[m][1] : (r16 == 2) ? rsum[m][2] : rsum[m][3];
            srow[mb + 16 * m + 4 * q4 + r16][wc] = v;
        }
    }
    // col sums within wave slice (128 rows): butterfly over q4; lanes<16 hold cols nb+16n+lane
#pragma unroll
    for (int n = 0; n < 4; n++) {
        float v = csum[n];
        v += __shfl_xor(v, 16);
        v += __shfl_xor(v, 32);
        if (lane < 16) scol[nb + 16 * n + lane][wr] = v;
    }
    __syncthreads();
    if (tid < 256) {
        float v = srow[tid][0] + srow[tid][1] + srow[tid][2] + srow[tid][3];
        pb[((size_t)bt * BB + b) * LQ + bq * BM + tid] = v;
        float u = scol[tid][0] + scol[tid][1];
        pa[((size_t)bq * BB + b) * LD + bt * BN + tid] = u;
    }
}

// K2: sum partials -> masked renormalized softmax. Blocks 0..31: alpha rows (n=2048, also
// zero d_out slice for k3's atomics); blocks 32..63: beta rows (n=512).
__global__ __launch_bounds__(256) void k2(const float* __restrict__ pa, const float* __restrict__ pb,
                                          const float* __restrict__ dmask, const float* __restrict__ qmask,
                                          float* __restrict__ alpha, float* __restrict__ beta,
                                          float* __restrict__ out) {
    __shared__ float sl[2048];
    __shared__ float sm[4], ss[4];
    int blk = blockIdx.x, tid = threadIdx.x, lane = tid & 63, wave = tid >> 6;
    const float* mk;
    float* dst;
    int n;
    if (blk < BB) {
        int b = blk;
        out[b * 2 * DD + tid] = 0.f;          // zero d_out for k3
        out[b * 2 * DD + 256 + tid] = 0.f;
        n = LD;
        mk = dmask + b * LD;
        dst = alpha + b * LD;
        for (int i = tid; i < n; i += 256)
            sl[i] = pa[(size_t)b * LD + i] + pa[((size_t)BB + b) * LD + i];
    } else {
        int b = blk - BB;
        n = LQ;
        mk = qmask + b * LQ;
        dst = beta + b * LQ;
        for (int i = tid; i < n; i += 256) {
            float s = 0.f;
#pragma unroll
            for (int bt = 0; bt < 8; bt++) s += pb[((size_t)bt * BB + b) * LQ + i];
            sl[i] = s;
        }
    }
    __syncthreads();
    float mx = -3.0e38f;
    for (int i = tid; i < n; i += 256) mx = fmaxf(mx, sl[i]);
#pragma unroll
    for (int s = 1; s < 64; s <<= 1) mx = fmaxf(mx, __shfl_xor(mx, s));
    if (lane == 0) sm[wave] = mx;
    __syncthreads();
    mx = fmaxf(fmaxf(sm[0], sm[1]), fmaxf(sm[2], sm[3]));
    const float L2E = 1.4426950408889634f;
    float sum = 0.f;
    for (int i = tid; i < n; i += 256) {
        float e = __builtin_amdgcn_exp2f((sl[i] - mx) * L2E) * mk[i];
        sl[i] = e;
        sum += e;
    }
#pragma unroll
    for (int s = 1; s < 64; s <<= 1) sum += __shfl_xor(sum, s);
    if (lane == 0) ss[wave] = sum;
    __syncthreads();
    sum = ss[0] + ss[1] + ss[2] + ss[3];
    float inv = 1.0f / sum;
    for (int i = tid; i < n; i += 256) dst[i] = sl[i] * inv;
}

// K3: weighted pooling, fp32 sources, coalesced float4 loads. Block = (b, 128-position chunk).
// Thread (g=tid>>5, c=tid&31): owns d-slice [8c,8c+8), strides g over positions.
__global__ __launch_bounds__(256) void k3(const float* __restrict__ docf, const float* __restrict__ qryf,
                                          const float* __restrict__ alpha, const float* __restrict__ beta,
                                          float* __restrict__ out) {
    __shared__ float sm[8 * DD];
    int blk = blockIdx.x, tid = threadIdx.x;
    const float* srcf;
    const float* w;
    float* dst;
    if (blk < BB * 16) {
        int b = blk >> 4, ch = blk & 15;
        srcf = docf + ((size_t)b * LD + ch * 128) * DD;
        w = alpha + b * LD + ch * 128;
        dst = out + b * 2 * DD;
    } else {
        int k = blk - BB * 16;
        int b = k >> 2, ch = k & 3;
        srcf = qryf + ((size_t)b * LQ + ch * 128) * DD;
        w = beta + b * LQ + ch * 128;
        dst = out + b * 2 * DD + DD;
    }
    int g = tid >> 5, c = tid & 31;
    float acc[8];
#pragma unroll
    for (int j = 0; j < 8; j++) acc[j] = 0.f;
    for (int r = 0; r < 16; r++) {
        int t = r * 8 + g;
        float wt = w[t];
        const float4v* p = (const float4v*)(srcf + (size_t)t * DD + c * 8);
        float4v x0 = p[0], x1 = p[1];
#pragma unroll
        for (int j = 0; j < 4; j++) { acc[j] += wt * x0[j]; acc[4 + j] += wt * x1[j]; }
    }
#pragma unroll
    for (int j = 0; j < 8; j++) sm[g * DD + c * 8 + j] = acc[j];
    __syncthreads();
    float s = 0.f;
#pragma unroll
    for (int g2 = 0; g2 < 8; g2++) s += sm[g2 * DD + tid];
    atomicAdd(dst + tid, s);
}

extern "C" void kernel_launch(void* const* d_in, const int* in_sizes, int n_in,
                              void* d_out, int out_size, void* d_ws, size_t ws_size,
                              hipStream_t stream) {
    (void)in_sizes; (void)n_in; (void)out_size; (void)ws_size;
    const float* doc = (const float*)d_in[0];
    const float* qry = (const float*)d_in[1];
    const float* dmask = (const float*)d_in[2];
    const float* qmask = (const float*)d_in[3];
    float* out = (float*)d_out;

    float* pa = (float*)d_ws;                   // [2][B][LD]
    float* pb = pa + 2 * BB * LD;               // [8][B][LQ]
    float* alpha = pb + 8 * BB * LQ;            // [B][LD]
    float* beta = alpha + BB * LD;              // [B][LQ]

    k1<<<dim3(LQ / BM, LD / BN, BB), 512, 0, stream>>>(qry, doc, pa, pb);
    k2<<<2 * BB, 256, 0, stream>>>(pa, pb, dmask, qmask, alpha, beta, out);
    k3<<<BB * 16 + BB * 4, 256, 0, stream>>>(doc, qry, alpha, beta, out);
}